// Round 1
// baseline (718.842 us; speedup 1.0000x reference)
//
#include <hip/hip_runtime.h>

#define N_NODES 50000
#define N_EDGES 800000
#define DIM 64

// ---------------------------------------------------------------------------
// Kernel 1: scatter-add  agg[dst[e]] += features[src[e]]
// 16 lanes per edge, each lane handles a float4 (16 B) of the 256 B row.
// ---------------------------------------------------------------------------
__global__ void gcn_scatter_kernel(const float* __restrict__ features,
                                   const int* __restrict__ src,
                                   const int* __restrict__ dst,
                                   float* __restrict__ agg) {
    int tid = blockIdx.x * blockDim.x + threadIdx.x;
    int e   = tid >> 4;       // edge index
    int c4  = tid & 15;       // which float4 of the 64-float row
    if (e >= N_EDGES) return;
    int s = src[e];
    int d = dst[e];
    const float4 v = ((const float4*)(features + (size_t)s * DIM))[c4];
    float* out = agg + (size_t)d * DIM + (size_t)c4 * 4;
    atomicAdd(out + 0, v.x);
    atomicAdd(out + 1, v.y);
    atomicAdd(out + 2, v.z);
    atomicAdd(out + 3, v.w);
}

// ---------------------------------------------------------------------------
// Kernel 2: in-place  h = relu(agg @ W^T + b)
// Block = 256 threads = 4 rows x 64 cols. W staged in LDS with +1 pad
// (bank = (j+k)%32 -> 2-way aliasing, free on CDNA4). Row reads are
// wave-uniform broadcasts from LDS.
// ---------------------------------------------------------------------------
__global__ void gcn_linear_relu_kernel(float* __restrict__ inout,
                                       const float* __restrict__ W,
                                       const float* __restrict__ b) {
    __shared__ float Ws[DIM][DIM + 1];
    __shared__ float rows[4][DIM];

    int t = threadIdx.x;
    // Stage W: 4096 floats, 16 per thread, coalesced.
    #pragma unroll
    for (int i = t; i < DIM * DIM; i += 256) {
        Ws[i >> 6][i & 63] = W[i];
    }

    int row_base = blockIdx.x * 4;
    int r = t >> 6;   // wave id = row within block (0..3)
    int j = t & 63;   // output column
    rows[r][j] = inout[(size_t)(row_base + r) * DIM + j];
    __syncthreads();

    float acc = b[j];
    #pragma unroll
    for (int k = 0; k < DIM; ++k) {
        acc = fmaf(rows[r][k], Ws[j][k], acc);
    }
    inout[(size_t)(row_base + r) * DIM + j] = fmaxf(acc, 0.0f);
}

extern "C" void kernel_launch(void* const* d_in, const int* in_sizes, int n_in,
                              void* d_out, int out_size, void* d_ws, size_t ws_size,
                              hipStream_t stream) {
    const float* features = (const float*)d_in[0];
    const int*   src      = (const int*)d_in[1];
    const int*   dst      = (const int*)d_in[2];
    const float* W        = (const float*)d_in[3];
    const float* b        = (const float*)d_in[4];
    float* out = (float*)d_out;

    // Zero the accumulator (d_out doubles as agg buffer).
    hipMemsetAsync(out, 0, (size_t)N_NODES * DIM * sizeof(float), stream);

    // Scatter: 800000 edges * 16 lanes = 12.8M threads, 256/block.
    {
        int total = N_EDGES * 16;
        int blocks = (total + 255) / 256;
        gcn_scatter_kernel<<<blocks, 256, 0, stream>>>(features, src, dst, out);
    }

    // Linear + bias + ReLU, in place: 50000 rows / 4 per block.
    {
        int blocks = N_NODES / 4;   // 50000 divisible by 4
        gcn_linear_relu_kernel<<<blocks, 256, 0, stream>>>(out, W, b);
    }
}

// Round 3
// 254.589 us; speedup vs baseline: 2.8235x; 2.8235x over previous
//
#include <hip/hip_runtime.h>

#define N_NODES 50000
#define N_EDGES 800000
#define DIM 64

// ---------------------------------------------------------------------------
// Workspace layout (ints):
//   counts  : [0, 50000)
//   offsets : [50000, 100001)     (50001 entries, exclusive prefix + total)
//   cursor  : [100001, 150001)
//   esorted : [150001, 950001)    (src node ids, grouped by dst)
// Total 950001 ints ~= 3.8 MB.
// ---------------------------------------------------------------------------
#define WS_INTS_NEEDED 950001u

// Kernel 1: histogram of dst
__global__ void gcn_hist_kernel(const int* __restrict__ dst,
                                int* __restrict__ counts) {
    int e = blockIdx.x * blockDim.x + threadIdx.x;
    if (e >= N_EDGES) return;
    atomicAdd(&counts[dst[e]], 1);
}

// Kernel 2: single-block exclusive scan of counts -> offsets (and cursor copy).
#define SCAN_THREADS 1024
#define SEG 49   // 1024*49 = 50176 >= 50000
__global__ void gcn_scan_kernel(const int* __restrict__ counts,
                                int* __restrict__ offsets,
                                int* __restrict__ cursor) {
    __shared__ int sums[SCAN_THREADS];
    int t = threadIdx.x;
    int beg = t * SEG;
    int end = beg + SEG; if (end > N_NODES) end = N_NODES;
    if (beg > N_NODES) beg = N_NODES;

    int local = 0;
    for (int i = beg; i < end; ++i) local += counts[i];
    sums[t] = local;
    __syncthreads();
    // Hillis-Steele inclusive scan
    for (int off = 1; off < SCAN_THREADS; off <<= 1) {
        int v = (t >= off) ? sums[t - off] : 0;
        __syncthreads();
        sums[t] += v;
        __syncthreads();
    }
    int base = sums[t] - local;   // exclusive prefix for this segment
    for (int i = beg; i < end; ++i) {
        offsets[i] = base;
        cursor[i]  = base;
        base += counts[i];
    }
    if (t == 0) offsets[N_NODES] = N_EDGES;
}

// Kernel 3: reorder edges by dst (counting-sort placement)
__global__ void gcn_reorder_kernel(const int* __restrict__ src,
                                   const int* __restrict__ dst,
                                   int* __restrict__ cursor,
                                   int* __restrict__ esorted) {
    int e = blockIdx.x * blockDim.x + threadIdx.x;
    if (e >= N_EDGES) return;
    int d = dst[e];
    int pos = atomicAdd(&cursor[d], 1);
    esorted[pos] = src[e];
}

// Kernel 4: fused gather-sum + linear + bias + ReLU.
// Block = 256 threads = 4 waves; wave w handles node blockIdx*4+w.
__global__ void gcn_gather_linear_kernel(const float* __restrict__ features,
                                         const int* __restrict__ esorted,
                                         const int* __restrict__ offsets,
                                         const float* __restrict__ W,
                                         const float* __restrict__ b,
                                         float* __restrict__ out) {
    __shared__ float Ws[DIM][DIM + 1];   // +1 pad: bank = (j+k)%32, 2-way (free)
    __shared__ float rows[4][DIM];

    int t = threadIdx.x;
    #pragma unroll
    for (int i = t; i < DIM * DIM; i += 256) {
        Ws[i >> 6][i & 63] = W[i];
    }

    int w    = t >> 6;
    int lane = t & 63;
    int node = blockIdx.x * 4 + w;

    int beg = offsets[node];
    int end = offsets[node + 1];

    float a0 = 0.f, a1 = 0.f, a2 = 0.f, a3 = 0.f;
    for (int base = beg; base < end; base += 64) {
        int m = end - base; if (m > 64) m = 64;
        int ids = (lane < m) ? esorted[base + lane] : 0;
        int k = 0;
        for (; k + 3 < m; k += 4) {
            int s0 = __shfl(ids, k);
            int s1 = __shfl(ids, k + 1);
            int s2 = __shfl(ids, k + 2);
            int s3 = __shfl(ids, k + 3);
            a0 += features[(size_t)s0 * DIM + lane];
            a1 += features[(size_t)s1 * DIM + lane];
            a2 += features[(size_t)s2 * DIM + lane];
            a3 += features[(size_t)s3 * DIM + lane];
        }
        for (; k < m; ++k) {
            int s = __shfl(ids, k);
            a0 += features[(size_t)s * DIM + lane];
        }
    }
    rows[w][lane] = (a0 + a1) + (a2 + a3);
    __syncthreads();

    float acc = b[lane];
    #pragma unroll
    for (int k = 0; k < DIM; ++k) {
        acc = fmaf(rows[w][k], Ws[lane][k], acc);   // rows: broadcast; Ws: 2-way
    }
    out[(size_t)node * DIM + lane] = fmaxf(acc, 0.f);
}

// ---------------------------------------------------------------------------
// Fallback path (used only if workspace is too small): atomic scatter + linear.
// ---------------------------------------------------------------------------
__global__ void gcn_scatter_kernel(const float* __restrict__ features,
                                   const int* __restrict__ src,
                                   const int* __restrict__ dst,
                                   float* __restrict__ agg) {
    int tid = blockIdx.x * blockDim.x + threadIdx.x;
    int e   = tid >> 4;
    int c4  = tid & 15;
    if (e >= N_EDGES) return;
    int s = src[e];
    int d = dst[e];
    const float4 v = ((const float4*)(features + (size_t)s * DIM))[c4];
    float* outp = agg + (size_t)d * DIM + (size_t)c4 * 4;
    atomicAdd(outp + 0, v.x);
    atomicAdd(outp + 1, v.y);
    atomicAdd(outp + 2, v.z);
    atomicAdd(outp + 3, v.w);
}

__global__ void gcn_linear_relu_kernel(float* __restrict__ inout,
                                       const float* __restrict__ W,
                                       const float* __restrict__ b) {
    __shared__ float Ws[DIM][DIM + 1];
    __shared__ float rows[4][DIM];
    int t = threadIdx.x;
    #pragma unroll
    for (int i = t; i < DIM * DIM; i += 256) {
        Ws[i >> 6][i & 63] = W[i];
    }
    int r = t >> 6;
    int j = t & 63;
    int row = blockIdx.x * 4 + r;
    rows[r][j] = inout[(size_t)row * DIM + j];
    __syncthreads();
    float acc = b[j];
    #pragma unroll
    for (int k = 0; k < DIM; ++k) {
        acc = fmaf(rows[r][k], Ws[j][k], acc);
    }
    inout[(size_t)row * DIM + j] = fmaxf(acc, 0.f);
}

extern "C" void kernel_launch(void* const* d_in, const int* in_sizes, int n_in,
                              void* d_out, int out_size, void* d_ws, size_t ws_size,
                              hipStream_t stream) {
    const float* features = (const float*)d_in[0];
    const int*   src      = (const int*)d_in[1];
    const int*   dst      = (const int*)d_in[2];
    const float* W        = (const float*)d_in[3];
    const float* b        = (const float*)d_in[4];
    float* out = (float*)d_out;

    int eblocks = (N_EDGES + 255) / 256;

    if (ws_size >= WS_INTS_NEEDED * sizeof(int)) {
        // CSR build + gather path (no f32 atomics).
        int* wsi     = (int*)d_ws;
        int* counts  = wsi;
        int* offsets = wsi + 50000;
        int* cursor  = wsi + 100001;
        int* esorted = wsi + 150001;

        hipMemsetAsync(counts, 0, (size_t)N_NODES * sizeof(int), stream);
        gcn_hist_kernel<<<eblocks, 256, 0, stream>>>(dst, counts);
        gcn_scan_kernel<<<1, SCAN_THREADS, 0, stream>>>(counts, offsets, cursor);
        gcn_reorder_kernel<<<eblocks, 256, 0, stream>>>(src, dst, cursor, esorted);
        gcn_gather_linear_kernel<<<N_NODES / 4, 256, 0, stream>>>(
            features, esorted, offsets, W, b, out);
    } else {
        // Fallback: atomic scatter into d_out, then in-place linear+ReLU.
        hipMemsetAsync(out, 0, (size_t)N_NODES * DIM * sizeof(float), stream);
        int total = N_EDGES * 16;
        gcn_scatter_kernel<<<(total + 255) / 256, 256, 0, stream>>>(features, src, dst, out);
        gcn_linear_relu_kernel<<<N_NODES / 4, 256, 0, stream>>>(out, W, b);
    }
}

// Round 4
// 158.331 us; speedup vs baseline: 4.5401x; 1.6080x over previous
//
#include <hip/hip_runtime.h>

#define N_NODES 50000
#define N_EDGES 800000
#define DIM 64

// ---------------------------------------------------------------------------
// Workspace layout (ints):
//   counts    : [0, 50000)
//   offsets   : [50000, 100001)     (50001 entries)
//   cursor    : [100001, 150001)
//   esorted   : [150001, 950001)    (src node ids, grouped by dst)
//   blocksums : [950001, 950197)    (196 entries)
//   blockoffs : [950197, 950393)
// Total 950393 ints ~= 3.8 MB.
// ---------------------------------------------------------------------------
#define SCAN_BLOCKS 196   // 196*256 = 50176 >= 50000
#define WS_INTS_NEEDED 950393u

// Kernel 1: histogram of dst
__global__ void gcn_hist_kernel(const int* __restrict__ dst,
                                int* __restrict__ counts) {
    int e = blockIdx.x * blockDim.x + threadIdx.x;
    if (e >= N_EDGES) return;
    atomicAdd(&counts[dst[e]], 1);
}

// Kernel 2a: per-block exclusive scan of counts; emit block totals.
__global__ void gcn_scanA_kernel(const int* __restrict__ counts,
                                 int* __restrict__ offsets,
                                 int* __restrict__ blocksums) {
    __shared__ int sums[256];
    int t = threadIdx.x;
    int i = blockIdx.x * 256 + t;
    int c = (i < N_NODES) ? counts[i] : 0;
    sums[t] = c;
    __syncthreads();
    #pragma unroll
    for (int off = 1; off < 256; off <<= 1) {
        int v = (t >= off) ? sums[t - off] : 0;
        __syncthreads();
        sums[t] += v;
        __syncthreads();
    }
    if (i < N_NODES) offsets[i] = sums[t] - c;   // exclusive, pre-blockoff
    if (t == 255) blocksums[blockIdx.x] = sums[255];
}

// Kernel 2b: single-block exclusive scan of the 196 block sums.
__global__ void gcn_scanB_kernel(const int* __restrict__ blocksums,
                                 int* __restrict__ blockoffs) {
    __shared__ int sums[256];
    int t = threadIdx.x;
    int c = (t < SCAN_BLOCKS) ? blocksums[t] : 0;
    sums[t] = c;
    __syncthreads();
    #pragma unroll
    for (int off = 1; off < 256; off <<= 1) {
        int v = (t >= off) ? sums[t - off] : 0;
        __syncthreads();
        sums[t] += v;
        __syncthreads();
    }
    if (t < SCAN_BLOCKS) blockoffs[t] = sums[t] - c;
}

// Kernel 2c: add block offsets; fill offsets + cursor.
__global__ void gcn_scanC_kernel(int* __restrict__ offsets,
                                 const int* __restrict__ blockoffs,
                                 int* __restrict__ cursor) {
    int t = threadIdx.x;
    int i = blockIdx.x * 256 + t;
    if (i < N_NODES) {
        int off = offsets[i] + blockoffs[blockIdx.x];
        offsets[i] = off;
        cursor[i]  = off;
    }
    if (i == 0) offsets[N_NODES] = N_EDGES;
}

// Kernel 3: reorder edges by dst (counting-sort placement)
__global__ void gcn_reorder_kernel(const int* __restrict__ src,
                                   const int* __restrict__ dst,
                                   int* __restrict__ cursor,
                                   int* __restrict__ esorted) {
    int e = blockIdx.x * blockDim.x + threadIdx.x;
    if (e >= N_EDGES) return;
    int d = dst[e];
    int pos = atomicAdd(&cursor[d], 1);
    esorted[pos] = src[e];
}

// Kernel 4: fused gather-sum + linear + bias + ReLU.
// Block = 256 threads = 4 waves; wave w handles node blockIdx*4+w.
__global__ void gcn_gather_linear_kernel(const float* __restrict__ features,
                                         const int* __restrict__ esorted,
                                         const int* __restrict__ offsets,
                                         const float* __restrict__ W,
                                         const float* __restrict__ b,
                                         float* __restrict__ out) {
    __shared__ float Ws[DIM][DIM + 1];   // +1 pad: bank = (j+k)%32, 2-way (free)
    __shared__ float rows[4][DIM];

    int t = threadIdx.x;
    #pragma unroll
    for (int i = t; i < DIM * DIM; i += 256) {
        Ws[i >> 6][i & 63] = W[i];
    }

    int w    = t >> 6;
    int lane = t & 63;
    int node = blockIdx.x * 4 + w;

    int beg = offsets[node];
    int end = offsets[node + 1];

    float a0 = 0.f, a1 = 0.f, a2 = 0.f, a3 = 0.f;
    for (int base = beg; base < end; base += 64) {
        int m = end - base; if (m > 64) m = 64;
        int ids = (lane < m) ? esorted[base + lane] : 0;
        int k = 0;
        for (; k + 3 < m; k += 4) {
            int s0 = __shfl(ids, k);
            int s1 = __shfl(ids, k + 1);
            int s2 = __shfl(ids, k + 2);
            int s3 = __shfl(ids, k + 3);
            a0 += features[(size_t)s0 * DIM + lane];
            a1 += features[(size_t)s1 * DIM + lane];
            a2 += features[(size_t)s2 * DIM + lane];
            a3 += features[(size_t)s3 * DIM + lane];
        }
        for (; k < m; ++k) {
            int s = __shfl(ids, k);
            a0 += features[(size_t)s * DIM + lane];
        }
    }
    rows[w][lane] = (a0 + a1) + (a2 + a3);
    __syncthreads();

    float acc = b[lane];
    #pragma unroll
    for (int k = 0; k < DIM; ++k) {
        acc = fmaf(rows[w][k], Ws[lane][k], acc);   // rows: broadcast; Ws: 2-way
    }
    out[(size_t)node * DIM + lane] = fmaxf(acc, 0.f);
}

// ---------------------------------------------------------------------------
// Fallback path (workspace too small): atomic scatter + linear.
// ---------------------------------------------------------------------------
__global__ void gcn_scatter_kernel(const float* __restrict__ features,
                                   const int* __restrict__ src,
                                   const int* __restrict__ dst,
                                   float* __restrict__ agg) {
    int tid = blockIdx.x * blockDim.x + threadIdx.x;
    int e   = tid >> 4;
    int c4  = tid & 15;
    if (e >= N_EDGES) return;
    int s = src[e];
    int d = dst[e];
    const float4 v = ((const float4*)(features + (size_t)s * DIM))[c4];
    float* outp = agg + (size_t)d * DIM + (size_t)c4 * 4;
    atomicAdd(outp + 0, v.x);
    atomicAdd(outp + 1, v.y);
    atomicAdd(outp + 2, v.z);
    atomicAdd(outp + 3, v.w);
}

__global__ void gcn_linear_relu_kernel(float* __restrict__ inout,
                                       const float* __restrict__ W,
                                       const float* __restrict__ b) {
    __shared__ float Ws[DIM][DIM + 1];
    __shared__ float rows[4][DIM];
    int t = threadIdx.x;
    #pragma unroll
    for (int i = t; i < DIM * DIM; i += 256) {
        Ws[i >> 6][i & 63] = W[i];
    }
    int r = t >> 6;
    int j = t & 63;
    int row = blockIdx.x * 4 + r;
    rows[r][j] = inout[(size_t)row * DIM + j];
    __syncthreads();
    float acc = b[j];
    #pragma unroll
    for (int k = 0; k < DIM; ++k) {
        acc = fmaf(rows[r][k], Ws[j][k], acc);
    }
    inout[(size_t)row * DIM + j] = fmaxf(acc, 0.f);
}

extern "C" void kernel_launch(void* const* d_in, const int* in_sizes, int n_in,
                              void* d_out, int out_size, void* d_ws, size_t ws_size,
                              hipStream_t stream) {
    const float* features = (const float*)d_in[0];
    const int*   src      = (const int*)d_in[1];
    const int*   dst      = (const int*)d_in[2];
    const float* W        = (const float*)d_in[3];
    const float* b        = (const float*)d_in[4];
    float* out = (float*)d_out;

    int eblocks = (N_EDGES + 255) / 256;

    if (ws_size >= WS_INTS_NEEDED * sizeof(int)) {
        int* wsi       = (int*)d_ws;
        int* counts    = wsi;
        int* offsets   = wsi + 50000;
        int* cursor    = wsi + 100001;
        int* esorted   = wsi + 150001;
        int* blocksums = wsi + 950001;
        int* blockoffs = wsi + 950197;

        hipMemsetAsync(counts, 0, (size_t)N_NODES * sizeof(int), stream);
        gcn_hist_kernel<<<eblocks, 256, 0, stream>>>(dst, counts);
        gcn_scanA_kernel<<<SCAN_BLOCKS, 256, 0, stream>>>(counts, offsets, blocksums);
        gcn_scanB_kernel<<<1, 256, 0, stream>>>(blocksums, blockoffs);
        gcn_scanC_kernel<<<SCAN_BLOCKS, 256, 0, stream>>>(offsets, blockoffs, cursor);
        gcn_reorder_kernel<<<eblocks, 256, 0, stream>>>(src, dst, cursor, esorted);
        gcn_gather_linear_kernel<<<N_NODES / 4, 256, 0, stream>>>(
            features, esorted, offsets, W, b, out);
    } else {
        hipMemsetAsync(out, 0, (size_t)N_NODES * DIM * sizeof(float), stream);
        int total = N_EDGES * 16;
        gcn_scatter_kernel<<<(total + 255) / 256, 256, 0, stream>>>(features, src, dst, out);
        gcn_linear_relu_kernel<<<N_NODES / 4, 256, 0, stream>>>(out, W, b);
    }
}